// Round 1
// baseline (474.357 us; speedup 1.0000x reference)
//
#include <hip/hip_runtime.h>
#include <math.h>

// Problem constants
#define NB 4
#define NC 128
#define NP 4096
#define KNN 10

// ---------------- ws layout (floats) ----------------
// Xcat : [B][N][512]  @ 0            (cols 0:128 x0, 128:256 x1, 256:512 x2)
// UV   : [B][N][512]  @ 8388608      (stage1 uses ld=256: [U(128)|V(128)])
// M    : [B][N][256]  @ 16777216     (stage1 ld=128). Y3 aliases M ([B][N][128])
// idx  : [B][N][10] i32 @ 20971520
// W1cat: [256][128]   @ 21135360
// W2cat: [512][128]   @ 21168128
// stats: [8192]       @ 21233664
// cand (d,i) alias UV base (used only during KNN, before UV is written)

__global__ void k_prep(const float* __restrict__ W1, const float* __restrict__ W2,
                       float* __restrict__ W1cat, float* __restrict__ W2cat,
                       float* __restrict__ stats) {
  int t = blockIdx.x * 256 + threadIdx.x;
  if (t < 32768) {
    int o = t >> 7, c = t & 127;
    float v;
    if (o < 128) v = W1[o * 256 + c] - W1[o * 256 + 128 + c];     // A1 = W1a - W1b
    else         v = W1[(o - 128) * 256 + 128 + c];               // B1 = W1b
    W1cat[t] = v;
  } else if (t < 98304) {
    int t2 = t - 32768;
    int o = t2 >> 7, c = t2 & 127;
    float v;
    if (o < 256) v = W2[o * 256 + c] - W2[o * 256 + 128 + c];     // A2
    else         v = W2[(o - 256) * 256 + 128 + c];               // B2
    W2cat[t2] = v;
  } else if (t < 98304 + 8192) {
    stats[t - 98304] = 0.f;
  }
}

// features [B][128][4096] -> Xcat[b][n][0:128]
__global__ void k_trans_feat(const float* __restrict__ feat, float* __restrict__ Xcat) {
  __shared__ float tile[32][33];
  int bid = blockIdx.x;           // 4 * 128 * 4 = 2048
  int b = bid >> 9;
  int r = bid & 511;
  int n0 = (r >> 2) << 5;
  int c0 = (r & 3) << 5;
  int tx = threadIdx.x & 31, ty = threadIdx.x >> 5;   // 256 threads
#pragma unroll
  for (int i = 0; i < 4; i++) {
    int c = c0 + ty + i * 8;
    tile[ty + i * 8][tx] = feat[(b * 128 + c) * 4096 + n0 + tx];
  }
  __syncthreads();
#pragma unroll
  for (int i = 0; i < 4; i++) {
    int n = n0 + ty + i * 8;
    Xcat[((b * 4096 + n) * 512) + c0 + tx] = tile[tx][ty + i * 8];
  }
}

// KNN partial: each block = (batch, 256-query group, 1024-point chunk)
__global__ void k_knn_part(const float* __restrict__ coords,
                           float* __restrict__ candd, int* __restrict__ candi) {
  __shared__ float4 sp[1024];
  int L = blockIdx.x;            // 256 blocks
  int b = L >> 6;
  int rem = L & 63;
  int qblk = rem >> 2;
  int ch = rem & 3;
  int m0 = ch << 10;
  const float* cb = coords + b * 3 * 4096;
  for (int m = threadIdx.x; m < 1024; m += 256) {
    float x = cb[m0 + m], y = cb[4096 + m0 + m], z = cb[8192 + m0 + m];
    sp[m] = make_float4(x, y, z, x * x + y * y + z * z);
  }
  __syncthreads();
  int q = (qblk << 8) + threadIdx.x;
  float qx = cb[q], qy = cb[4096 + q], qz = cb[8192 + q];
  float qsq = qx * qx + qy * qy + qz * qz;
  float d10[10]; int i10[10];
#pragma unroll
  for (int i = 0; i < 10; i++) { d10[i] = 1e30f; i10[i] = -1; }
  for (int mm = 0; mm < 1024; mm++) {
    float4 p = sp[mm];
    int m = m0 + mm;
    float dot = fmaf(qx, p.x, fmaf(qy, p.y, qz * p.z));
    float d = qsq + p.w - 2.f * dot;
    if (d < d10[9] && m != q) {
      float cd = d; int ci = m;
#pragma unroll
      for (int i = 0; i < 10; i++) {
        bool lt = cd < d10[i];
        float nd = lt ? cd : d10[i]; int ni = lt ? ci : i10[i];
        float pd = lt ? d10[i] : cd; int pi2 = lt ? i10[i] : ci;
        d10[i] = nd; i10[i] = ni; cd = pd; ci = pi2;
      }
    }
  }
  int base = ((b * 4096 + q) * 4 + ch) * 10;
#pragma unroll
  for (int i = 0; i < 10; i++) { candd[base + i] = d10[i]; candi[base + i] = i10[i]; }
}

__global__ void k_knn_merge(const float* __restrict__ candd, const int* __restrict__ candi,
                            int* __restrict__ idx) {
  int t = blockIdx.x * 256 + threadIdx.x;  // 16384
  float d10[10]; int i10[10];
#pragma unroll
  for (int i = 0; i < 10; i++) { d10[i] = 1e30f; i10[i] = -1; }
  int base = t * 40;
  for (int j = 0; j < 40; j++) {
    float d = candd[base + j]; int m = candi[base + j];
    if (d < d10[9]) {
      float cd = d; int ci = m;
#pragma unroll
      for (int i = 0; i < 10; i++) {
        bool lt = cd < d10[i];
        float nd = lt ? cd : d10[i]; int ni = lt ? ci : i10[i];
        float pd = lt ? d10[i] : cd; int pi2 = lt ? i10[i] : ci;
        d10[i] = nd; i10[i] = ni; cd = pd; ci = pi2;
      }
    }
  }
#pragma unroll
  for (int i = 0; i < 10; i++) idx[t * 10 + i] = i10[i];
}

// fp32 GEMM: Y[p][o] = sum_k X[p*ldx+xoff+k] * W[o*ldw+k]
// BM=128, BN=64, BK=32, 128 threads, 8x8 micro-tile.
__global__ void k_gemm(const float* __restrict__ X, int ldx, int xoff,
                       const float* __restrict__ W, int ldw,
                       float* __restrict__ Y, int ldy,
                       int K) {
  __shared__ float Xs[32][132];
  __shared__ float Ws[32][68];
  int p0 = blockIdx.x * 128;
  int o0 = blockIdx.y * 64;
  int t = threadIdx.x;
  int tp = t & 15, to = t >> 4;    // to 0..7
  float acc[8][8];
#pragma unroll
  for (int i = 0; i < 8; i++)
#pragma unroll
    for (int j = 0; j < 8; j++) acc[i][j] = 0.f;

  int kk = (t & 7) * 4;
  int rr = t >> 3;                 // 0..15
  for (int k0 = 0; k0 < K; k0 += 32) {
#pragma unroll
    for (int pass = 0; pass < 8; pass++) {
      int r = rr + pass * 16;
      const float4 v = *(const float4*)&X[(p0 + r) * ldx + xoff + k0 + kk];
      Xs[kk + 0][r] = v.x; Xs[kk + 1][r] = v.y; Xs[kk + 2][r] = v.z; Xs[kk + 3][r] = v.w;
    }
#pragma unroll
    for (int pass = 0; pass < 4; pass++) {
      int r = rr + pass * 16;
      const float4 v = *(const float4*)&W[(o0 + r) * ldw + k0 + kk];
      Ws[kk + 0][r] = v.x; Ws[kk + 1][r] = v.y; Ws[kk + 2][r] = v.z; Ws[kk + 3][r] = v.w;
    }
    __syncthreads();
#pragma unroll 8
    for (int k = 0; k < 32; k++) {
      const float4 xa0 = *(const float4*)&Xs[k][tp * 8];
      const float4 xa1 = *(const float4*)&Xs[k][tp * 8 + 4];
      const float4 wb0 = *(const float4*)&Ws[k][to * 8];
      const float4 wb1 = *(const float4*)&Ws[k][to * 8 + 4];
      float xs[8] = {xa0.x, xa0.y, xa0.z, xa0.w, xa1.x, xa1.y, xa1.z, xa1.w};
      float wv[8] = {wb0.x, wb0.y, wb0.z, wb0.w, wb1.x, wb1.y, wb1.z, wb1.w};
#pragma unroll
      for (int i = 0; i < 8; i++)
#pragma unroll
        for (int j = 0; j < 8; j++) acc[i][j] = fmaf(xs[i], wv[j], acc[i][j]);
    }
    __syncthreads();
  }
#pragma unroll
  for (int i = 0; i < 8; i++) {
    int p = p0 + tp * 8 + i;
    float4 s0 = make_float4(acc[i][0], acc[i][1], acc[i][2], acc[i][3]);
    float4 s1 = make_float4(acc[i][4], acc[i][5], acc[i][6], acc[i][7]);
    *(float4*)&Y[p * ldy + o0 + to * 8]     = s0;
    *(float4*)&Y[p * ldy + o0 + to * 8 + 4] = s1;
  }
}

// Gather pass: per (b, 16-point group), O threads. Computes per-point max_k V,
// accumulates sum(U+V) and sum((U+V)^2) into per-(b,o) stats via one atomic each.
template <int O>
__global__ void k_gather(const float* __restrict__ UV, int ld, int voff,
                         const int* __restrict__ idx,
                         float* __restrict__ M,
                         float* __restrict__ T1, float* __restrict__ T2) {
  int L = blockIdx.x;             // 1024 blocks, XCD-affine: L%8 -> xcd, b = (L%8)>>1
  int rx = L & 7;
  int b = rx >> 1;
  int j = ((L >> 3) << 1) + (rx & 1);
  int n0 = j << 4;
  int o = threadIdx.x;
  float a1 = 0.f, a2 = 0.f;
  for (int pi = 0; pi < 16; pi++) {
    int row = b * 4096 + n0 + pi;
    float u = UV[row * ld + o];
    float s1 = 0.f, s2 = 0.f, vmax = -1e30f;
#pragma unroll
    for (int jj = 0; jj < KNN; jj++) {
      int m = idx[row * 10 + jj];
      float v = UV[(b * 4096 + m) * ld + voff + o];
      s1 += v;
      float x = u + v;
      s2 = fmaf(x, x, s2);
      vmax = fmaxf(vmax, v);
    }
    M[row * O + o] = vmax;
    a1 += 10.f * u + s1;
    a2 += s2;
  }
  atomicAdd(&T1[b * O + o], a1);
  atomicAdd(&T2[b * O + o], a2);
}

// x = lrelu((U + maxV - mu) * rsqrt(var+eps)) -> Xcat[:, coff:coff+O]
template <int O>
__global__ void k_passB(const float* __restrict__ UV, int ld,
                        const float* __restrict__ M, int coff,
                        const float* __restrict__ T1, const float* __restrict__ T2,
                        float* __restrict__ Xcat) {
  int t = blockIdx.x * 256 + threadIdx.x;
  int o = t & (O - 1);
  int pn = t / O;
  int b = pn >> 12;
  float mu = T1[b * O + o] * (1.f / 40960.f);
  float e2 = T2[b * O + o] * (1.f / 40960.f);
  float inv = rsqrtf(e2 - mu * mu + 1e-5f);
  float x = (UV[pn * ld + o] + M[pn * O + o] - mu) * inv;
  Xcat[pn * 512 + coff + o] = x >= 0.f ? x : 0.2f * x;
}

__global__ void k_stats3(const float* __restrict__ Y3, float* __restrict__ T1, float* __restrict__ T2) {
  int L = blockIdx.x;             // 1024
  int rx = L & 7;
  int b = rx >> 1;
  int j = ((L >> 3) << 1) + (rx & 1);
  int n0 = j << 4;
  int o = threadIdx.x;            // 128
  float a1 = 0.f, a2 = 0.f;
  for (int pi = 0; pi < 16; pi++) {
    float y = Y3[(b * 4096 + n0 + pi) * 128 + o];
    a1 += y;
    a2 = fmaf(y, y, a2);
  }
  atomicAdd(&T1[b * 128 + o], a1);
  atomicAdd(&T2[b * 128 + o], a2);
}

// out[b][o][n] = lrelu((Y3[b][n][o]-mu)*inv)  (transposing write)
__global__ void k_out(const float* __restrict__ Y3, const float* __restrict__ T1,
                      const float* __restrict__ T2, float* __restrict__ out) {
  __shared__ float tile[32][33];
  int bid = blockIdx.x;           // 2048
  int b = bid >> 9;
  int r = bid & 511;
  int n0 = (r >> 2) << 5;
  int o0 = (r & 3) << 5;
  int tx = threadIdx.x & 31, ty = threadIdx.x >> 5;
  int o = o0 + tx;
  float mu = T1[b * 128 + o] * (1.f / 4096.f);
  float e2 = T2[b * 128 + o] * (1.f / 4096.f);
  float inv = rsqrtf(e2 - mu * mu + 1e-5f);
#pragma unroll
  for (int i = 0; i < 4; i++) {
    int n = n0 + ty + i * 8;
    float v = (Y3[(b * 4096 + n) * 128 + o] - mu) * inv;
    tile[ty + i * 8][tx] = v >= 0.f ? v : 0.2f * v;
  }
  __syncthreads();
#pragma unroll
  for (int i = 0; i < 4; i++) {
    int oo = o0 + ty + i * 8;
    out[(b * 128 + oo) * 4096 + n0 + tx] = tile[tx][ty + i * 8];
  }
}

extern "C" void kernel_launch(void* const* d_in, const int* in_sizes, int n_in,
                              void* d_out, int out_size, void* d_ws, size_t ws_size,
                              hipStream_t stream) {
  const float* coords   = (const float*)d_in[0];
  const float* features = (const float*)d_in[1];
  const float* W1       = (const float*)d_in[2];
  const float* W2       = (const float*)d_in[3];
  const float* W3       = (const float*)d_in[4];
  float* out = (float*)d_out;

  float* ws    = (float*)d_ws;
  float* Xcat  = ws;
  float* UV    = ws + 8388608;
  float* Mbuf  = ws + 16777216;
  float* Y3    = Mbuf;                       // alias (M dead by fuse GEMM)
  int*   idxb  = (int*)(ws + 20971520);
  float* W1cat = ws + 21135360;
  float* W2cat = ws + 21168128;
  float* stats = ws + 21233664;
  float* candd = UV;                         // alias (pre-GEMM only)
  int*   candi = (int*)(UV + 655360);

  k_prep<<<416, 256, 0, stream>>>(W1, W2, W1cat, W2cat, stats);
  k_trans_feat<<<2048, 256, 0, stream>>>(features, Xcat);
  k_knn_part<<<256, 256, 0, stream>>>(coords, candd, candi);
  k_knn_merge<<<64, 256, 0, stream>>>(candd, candi, idxb);

  // stage 1: UV = Xcat[:, 0:128] @ W1cat^T  (O=256)
  k_gemm<<<dim3(128, 4), 128, 0, stream>>>(Xcat, 512, 0, W1cat, 128, UV, 256, 128);
  k_gather<128><<<1024, 128, 0, stream>>>(UV, 256, 128, idxb, Mbuf, stats + 0, stats + 512);
  k_passB<128><<<8192, 256, 0, stream>>>(UV, 256, Mbuf, 128, stats + 0, stats + 512, Xcat);

  // stage 2: UV = Xcat[:, 128:256] @ W2cat^T (O=512)
  k_gemm<<<dim3(128, 8), 128, 0, stream>>>(Xcat, 512, 128, W2cat, 128, UV, 512, 128);
  k_gather<256><<<1024, 256, 0, stream>>>(UV, 512, 256, idxb, Mbuf, stats + 1024, stats + 2048);
  k_passB<256><<<16384, 256, 0, stream>>>(UV, 512, Mbuf, 256, stats + 1024, stats + 2048, Xcat);

  // fuse: Y3 = Xcat[:, 0:512] @ W3^T (O=128)
  k_gemm<<<dim3(128, 2), 128, 0, stream>>>(Xcat, 512, 0, W3, 512, Y3, 128, 512);
  k_stats3<<<1024, 128, 0, stream>>>(Y3, stats + 3072, stats + 3584);
  k_out<<<2048, 256, 0, stream>>>(Y3, stats + 3072, stats + 3584, out);
}

// Round 3
// 373.184 us; speedup vs baseline: 1.2711x; 1.2711x over previous
//
#include <hip/hip_runtime.h>
#include <math.h>

// Problem constants
#define NB 4
#define NC 128
#define NP 4096
#define KNN 10

// ---------------- ws layout (floats) ----------------
// Xcat : [B][N][512]  @ 0            (cols 0:128 x0, 128:256 x1, 256:512 x2)
// UV   : [B][N][512]  @ 8388608      (stage1 uses ld=256: [U(128)|V(128)])
// M    : [B][N][256]  @ 16777216     (stage1 ld=128). Y3 aliases M ([B][N][128])
// idx  : [B][N][10] i32 @ 20971520
// W1cat: [256][128]   @ 21135360
// W2cat: [512][128]   @ 21168128
// stats: [8192]       @ 21233664
// KNN scratch aliases UV region (pre-GEMM only):
//   candd: [16384][160] @ UV+0
//   tq   : [16384]      @ UV+2621440
//   cd   : [16384][24]  @ UV+2637824
//   ci   : [16384][24]  @ UV+3031040 (int)
//   cnt  : [16384]      @ UV+3424256 (int)

__global__ void k_prep(const float* __restrict__ W1, const float* __restrict__ W2,
                       float* __restrict__ W1cat, float* __restrict__ W2cat,
                       float* __restrict__ stats, int* __restrict__ cnt) {
  int t = blockIdx.x * 256 + threadIdx.x;
  if (t < 32768) {
    int o = t >> 7, c = t & 127;
    float v;
    if (o < 128) v = W1[o * 256 + c] - W1[o * 256 + 128 + c];     // A1 = W1a - W1b
    else         v = W1[(o - 128) * 256 + 128 + c];               // B1 = W1b
    W1cat[t] = v;
  } else if (t < 98304) {
    int t2 = t - 32768;
    int o = t2 >> 7, c = t2 & 127;
    float v;
    if (o < 256) v = W2[o * 256 + c] - W2[o * 256 + 128 + c];     // A2
    else         v = W2[(o - 256) * 256 + 128 + c];               // B2
    W2cat[t2] = v;
  } else if (t < 98304 + 8192) {
    stats[t - 98304] = 0.f;
  } else if (t < 98304 + 8192 + 16384) {
    cnt[t - 98304 - 8192] = 0;
  }
}

// features [B][128][4096] -> Xcat[b][n][0:128]
__global__ void k_trans_feat(const float* __restrict__ feat, float* __restrict__ Xcat) {
  __shared__ float tile[32][33];
  int bid = blockIdx.x;           // 4 * 128 * 4 = 2048
  int b = bid >> 9;
  int r = bid & 511;
  int n0 = (r >> 2) << 5;
  int c0 = (r & 3) << 5;
  int tx = threadIdx.x & 31, ty = threadIdx.x >> 5;   // 256 threads
#pragma unroll
  for (int i = 0; i < 4; i++) {
    int c = c0 + ty + i * 8;
    tile[ty + i * 8][tx] = feat[(b * 128 + c) * 4096 + n0 + tx];
  }
  __syncthreads();
#pragma unroll
  for (int i = 0; i < 4; i++) {
    int n = n0 + ty + i * 8;
    Xcat[((b * 4096 + n) * 512) + c0 + tx] = tile[tx][ty + i * 8];
  }
}

// ---------------- KNN: exact 2-phase threshold scheme ----------------
// d = (qsq + |p|^2) - 2 q.p  -- SAME magnitude structure as the reference
// (sq_n + sq_m - 2 dot) so fp rounding noise correlates with the reference's.
// Written with explicit fmaf so Phase A and Phase C are bit-identical.
__global__ void k_knn_thr(const float* __restrict__ coords, float* __restrict__ candd) {
  __shared__ float4 sp[256];
  int L = blockIdx.x;             // 1024 = b(4) x qblk(16) x ch(16)
  int ch = L & 15;
  int qblk = (L >> 4) & 15;
  int b = L >> 8;
  int m0 = ch << 8;
  const float* cb = coords + b * 12288;
  int t = threadIdx.x;
  {
    int m = m0 + t;
    float x = cb[m], y = cb[4096 + m], z = cb[8192 + m];
    sp[t] = make_float4(x, y, z, x * x + y * y + z * z);
  }
  __syncthreads();
  int q = (qblk << 8) + t;
  float qx = cb[q], qy = cb[4096 + q], qz = cb[8192 + q];
  float qsq = fmaf(qx, qx, fmaf(qy, qy, qz * qz));
  float d10[10];
#pragma unroll
  for (int i = 0; i < 10; i++) d10[i] = 1e30f;
  if (ch == qblk) {               // block-uniform: this chunk contains self
#pragma unroll 4
    for (int mm = 0; mm < 256; mm++) {
      float4 p = sp[mm];
      float dot = fmaf(qx, p.x, fmaf(qy, p.y, qz * p.z));
      float s = qsq + p.w;
      float d = fmaf(-2.f, dot, s);
      d = (m0 + mm == q) ? 1e30f : d;
      float carry = d;
#pragma unroll
      for (int i = 0; i < 10; i++) {
        float lo = fminf(d10[i], carry);
        carry = fmaxf(d10[i], carry);
        d10[i] = lo;
      }
    }
  } else {
#pragma unroll 4
    for (int mm = 0; mm < 256; mm++) {
      float4 p = sp[mm];
      float dot = fmaf(qx, p.x, fmaf(qy, p.y, qz * p.z));
      float s = qsq + p.w;
      float d = fmaf(-2.f, dot, s);
      float carry = d;
#pragma unroll
      for (int i = 0; i < 10; i++) {
        float lo = fminf(d10[i], carry);
        carry = fmaxf(d10[i], carry);
        d10[i] = lo;
      }
    }
  }
  int base = ((b * 4096 + q) * 16 + ch) * 10;
#pragma unroll
  for (int i = 0; i < 10; i++) candd[base + i] = d10[i];
}

// Phase B: per query merge 160 values -> exact 10th smallest threshold
__global__ void k_knn_merge(const float* __restrict__ candd, float* __restrict__ tq) {
  int q = blockIdx.x * 256 + threadIdx.x;  // 16384
  float d10[10];
#pragma unroll
  for (int i = 0; i < 10; i++) d10[i] = 1e30f;
  const float4* cp = (const float4*)(candd + q * 160);
  for (int j = 0; j < 40; j++) {
    float4 v4 = cp[j];
    float vs[4] = {v4.x, v4.y, v4.z, v4.w};
#pragma unroll
    for (int u = 0; u < 4; u++) {
      float carry = vs[u];
#pragma unroll
      for (int i = 0; i < 10; i++) {
        float lo = fminf(d10[i], carry);
        carry = fmaxf(d10[i], carry);
        d10[i] = lo;
      }
    }
  }
  tq[q] = d10[9];
}

// Phase C: rescan (bit-identical distance), collect indices with d <= t
__global__ void k_knn_collect(const float* __restrict__ coords, const float* __restrict__ tq,
                              int* __restrict__ cnt, float* __restrict__ cd, int* __restrict__ ci) {
  __shared__ float4 sp[256];
  int L = blockIdx.x;             // 1024
  int ch = L & 15;
  int qblk = (L >> 4) & 15;
  int b = L >> 8;
  int m0 = ch << 8;
  const float* cb = coords + b * 12288;
  int t = threadIdx.x;
  {
    int m = m0 + t;
    float x = cb[m], y = cb[4096 + m], z = cb[8192 + m];
    sp[t] = make_float4(x, y, z, x * x + y * y + z * z);
  }
  __syncthreads();
  int q = (qblk << 8) + t;
  int row = b * 4096 + q;
  float qx = cb[q], qy = cb[4096 + q], qz = cb[8192 + q];
  float qsq = fmaf(qx, qx, fmaf(qy, qy, qz * qz));
  float thr = tq[row];
  bool hs = (ch == qblk);
  for (int mm = 0; mm < 256; mm++) {
    float4 p = sp[mm];
    float dot = fmaf(qx, p.x, fmaf(qy, p.y, qz * p.z));
    float s = qsq + p.w;
    float d = fmaf(-2.f, dot, s);
    int m = m0 + mm;
    if (d <= thr && !(hs && m == q)) {
      int pos = atomicAdd(&cnt[row], 1);
      if (pos < 24) { cd[row * 24 + pos] = d; ci[row * 24 + pos] = m; }
    }
  }
}

// Phase D: exact (d, idx) lexicographic top-10 of the <=24 candidates
__global__ void k_knn_final(const int* __restrict__ cnt, const float* __restrict__ cd,
                            const int* __restrict__ ci, int* __restrict__ idx) {
  int row = blockIdx.x * 256 + threadIdx.x;  // 16384
  int c = cnt[row]; c = c < 24 ? c : 24;
  float d10[10]; int i10[10];
#pragma unroll
  for (int i = 0; i < 10; i++) { d10[i] = 1e30f; i10[i] = 0x7fffffff; }
  for (int j = 0; j < c; j++) {
    float cdv = cd[row * 24 + j]; int civ = ci[row * 24 + j];
#pragma unroll
    for (int i = 0; i < 10; i++) {
      bool lt = (cdv < d10[i]) || (cdv == d10[i] && civ < i10[i]);
      float nd = lt ? cdv : d10[i]; int ni = lt ? civ : i10[i];
      float pd = lt ? d10[i] : cdv; int pi2 = lt ? i10[i] : civ;
      d10[i] = nd; i10[i] = ni; cdv = pd; civ = pi2;
    }
  }
#pragma unroll
  for (int i = 0; i < 10; i++) idx[row * 10 + i] = i10[i];
}

// fp32 GEMM: Y[p][o] = sum_k X[p*ldx+xoff+k] * W[o*ldw+k]
// BM=128, BN=64, BK=32, 128 threads, 8x8 micro-tile.
__global__ void k_gemm(const float* __restrict__ X, int ldx, int xoff,
                       const float* __restrict__ W, int ldw,
                       float* __restrict__ Y, int ldy,
                       int K) {
  __shared__ float Xs[32][132];
  __shared__ float Ws[32][68];
  int p0 = blockIdx.x * 128;
  int o0 = blockIdx.y * 64;
  int t = threadIdx.x;
  int tp = t & 15, to = t >> 4;    // to 0..7
  float acc[8][8];
#pragma unroll
  for (int i = 0; i < 8; i++)
#pragma unroll
    for (int j = 0; j < 8; j++) acc[i][j] = 0.f;

  int kk = (t & 7) * 4;
  int rr = t >> 3;                 // 0..15
  for (int k0 = 0; k0 < K; k0 += 32) {
#pragma unroll
    for (int pass = 0; pass < 8; pass++) {
      int r = rr + pass * 16;
      const float4 v = *(const float4*)&X[(p0 + r) * ldx + xoff + k0 + kk];
      Xs[kk + 0][r] = v.x; Xs[kk + 1][r] = v.y; Xs[kk + 2][r] = v.z; Xs[kk + 3][r] = v.w;
    }
#pragma unroll
    for (int pass = 0; pass < 4; pass++) {
      int r = rr + pass * 16;
      const float4 v = *(const float4*)&W[(o0 + r) * ldw + k0 + kk];
      Ws[kk + 0][r] = v.x; Ws[kk + 1][r] = v.y; Ws[kk + 2][r] = v.z; Ws[kk + 3][r] = v.w;
    }
    __syncthreads();
#pragma unroll 8
    for (int k = 0; k < 32; k++) {
      const float4 xa0 = *(const float4*)&Xs[k][tp * 8];
      const float4 xa1 = *(const float4*)&Xs[k][tp * 8 + 4];
      const float4 wb0 = *(const float4*)&Ws[k][to * 8];
      const float4 wb1 = *(const float4*)&Ws[k][to * 8 + 4];
      float xs[8] = {xa0.x, xa0.y, xa0.z, xa0.w, xa1.x, xa1.y, xa1.z, xa1.w};
      float wv[8] = {wb0.x, wb0.y, wb0.z, wb0.w, wb1.x, wb1.y, wb1.z, wb1.w};
#pragma unroll
      for (int i = 0; i < 8; i++)
#pragma unroll
        for (int j = 0; j < 8; j++) acc[i][j] = fmaf(xs[i], wv[j], acc[i][j]);
    }
    __syncthreads();
  }
#pragma unroll
  for (int i = 0; i < 8; i++) {
    int p = p0 + tp * 8 + i;
    float4 s0 = make_float4(acc[i][0], acc[i][1], acc[i][2], acc[i][3]);
    float4 s1 = make_float4(acc[i][4], acc[i][5], acc[i][6], acc[i][7]);
    *(float4*)&Y[p * ldy + o0 + to * 8]     = s0;
    *(float4*)&Y[p * ldy + o0 + to * 8 + 4] = s1;
  }
}

// Gather pass: per (b, 16-point group), O threads. Computes per-point max_k V,
// accumulates sum(U+V) and sum((U+V)^2) into per-(b,o) stats via one atomic each.
template <int O>
__global__ void k_gather(const float* __restrict__ UV, int ld, int voff,
                         const int* __restrict__ idx,
                         float* __restrict__ M,
                         float* __restrict__ T1, float* __restrict__ T2) {
  int L = blockIdx.x;             // 1024 blocks
  int rx = L & 7;
  int b = rx >> 1;
  int j = ((L >> 3) << 1) + (rx & 1);
  int n0 = j << 4;
  int o = threadIdx.x;
  float a1 = 0.f, a2 = 0.f;
  for (int pi = 0; pi < 16; pi++) {
    int row = b * 4096 + n0 + pi;
    float u = UV[row * ld + o];
    float s1 = 0.f, s2 = 0.f, vmax = -1e30f;
#pragma unroll
    for (int jj = 0; jj < KNN; jj++) {
      int m = idx[row * 10 + jj];
      float v = UV[(b * 4096 + m) * ld + voff + o];
      s1 += v;
      float x = u + v;
      s2 = fmaf(x, x, s2);
      vmax = fmaxf(vmax, v);
    }
    M[row * O + o] = vmax;
    a1 += 10.f * u + s1;
    a2 += s2;
  }
  atomicAdd(&T1[b * O + o], a1);
  atomicAdd(&T2[b * O + o], a2);
}

// x = lrelu((U + maxV - mu) * rsqrt(var+eps)) -> Xcat[:, coff:coff+O]
template <int O>
__global__ void k_passB(const float* __restrict__ UV, int ld,
                        const float* __restrict__ M, int coff,
                        const float* __restrict__ T1, const float* __restrict__ T2,
                        float* __restrict__ Xcat) {
  int t = blockIdx.x * 256 + threadIdx.x;
  int o = t & (O - 1);
  int pn = t / O;
  int b = pn >> 12;
  float mu = T1[b * O + o] * (1.f / 40960.f);
  float e2 = T2[b * O + o] * (1.f / 40960.f);
  float inv = rsqrtf(e2 - mu * mu + 1e-5f);
  float x = (UV[pn * ld + o] + M[pn * O + o] - mu) * inv;
  Xcat[pn * 512 + coff + o] = x >= 0.f ? x : 0.2f * x;
}

__global__ void k_stats3(const float* __restrict__ Y3, float* __restrict__ T1, float* __restrict__ T2) {
  int L = blockIdx.x;             // 1024
  int rx = L & 7;
  int b = rx >> 1;
  int j = ((L >> 3) << 1) + (rx & 1);
  int n0 = j << 4;
  int o = threadIdx.x;            // 128
  float a1 = 0.f, a2 = 0.f;
  for (int pi = 0; pi < 16; pi++) {
    float y = Y3[(b * 4096 + n0 + pi) * 128 + o];
    a1 += y;
    a2 = fmaf(y, y, a2);
  }
  atomicAdd(&T1[b * 128 + o], a1);
  atomicAdd(&T2[b * 128 + o], a2);
}

// out[b][o][n] = lrelu((Y3[b][n][o]-mu)*inv)  (transposing write)
__global__ void k_out(const float* __restrict__ Y3, const float* __restrict__ T1,
                      const float* __restrict__ T2, float* __restrict__ out) {
  __shared__ float tile[32][33];
  int bid = blockIdx.x;           // 2048
  int b = bid >> 9;
  int r = bid & 511;
  int n0 = (r >> 2) << 5;
  int o0 = (r & 3) << 5;
  int tx = threadIdx.x & 31, ty = threadIdx.x >> 5;
  int o = o0 + tx;
  float mu = T1[b * 128 + o] * (1.f / 4096.f);
  float e2 = T2[b * 128 + o] * (1.f / 4096.f);
  float inv = rsqrtf(e2 - mu * mu + 1e-5f);
#pragma unroll
  for (int i = 0; i < 4; i++) {
    int n = n0 + ty + i * 8;
    float v = (Y3[(b * 4096 + n) * 128 + o] - mu) * inv;
    tile[ty + i * 8][tx] = v >= 0.f ? v : 0.2f * v;
  }
  __syncthreads();
#pragma unroll
  for (int i = 0; i < 4; i++) {
    int oo = o0 + ty + i * 8;
    out[(b * 128 + oo) * 4096 + n0 + tx] = tile[tx][ty + i * 8];
  }
}

extern "C" void kernel_launch(void* const* d_in, const int* in_sizes, int n_in,
                              void* d_out, int out_size, void* d_ws, size_t ws_size,
                              hipStream_t stream) {
  const float* coords   = (const float*)d_in[0];
  const float* features = (const float*)d_in[1];
  const float* W1       = (const float*)d_in[2];
  const float* W2       = (const float*)d_in[3];
  const float* W3       = (const float*)d_in[4];
  float* out = (float*)d_out;

  float* ws    = (float*)d_ws;
  float* Xcat  = ws;
  float* UV    = ws + 8388608;
  float* Mbuf  = ws + 16777216;
  float* Y3    = Mbuf;                       // alias (M dead by fuse GEMM)
  int*   idxb  = (int*)(ws + 20971520);
  float* W1cat = ws + 21135360;
  float* W2cat = ws + 21168128;
  float* stats = ws + 21233664;
  // KNN scratch aliases UV region (used only before stage-1 GEMM)
  float* candd = UV;
  float* tq    = UV + 2621440;
  float* cd    = UV + 2637824;
  int*   ci    = (int*)(UV + 3031040);
  int*   cnt   = (int*)(UV + 3424256);

  k_prep<<<480, 256, 0, stream>>>(W1, W2, W1cat, W2cat, stats, cnt);
  k_trans_feat<<<2048, 256, 0, stream>>>(features, Xcat);
  k_knn_thr<<<1024, 256, 0, stream>>>(coords, candd);
  k_knn_merge<<<64, 256, 0, stream>>>(candd, tq);
  k_knn_collect<<<1024, 256, 0, stream>>>(coords, tq, cnt, cd, ci);
  k_knn_final<<<64, 256, 0, stream>>>(cnt, cd, ci, idxb);

  // stage 1: UV = Xcat[:, 0:128] @ W1cat^T  (O=256)
  k_gemm<<<dim3(128, 4), 128, 0, stream>>>(Xcat, 512, 0, W1cat, 128, UV, 256, 128);
  k_gather<128><<<1024, 128, 0, stream>>>(UV, 256, 128, idxb, Mbuf, stats + 0, stats + 512);
  k_passB<128><<<8192, 256, 0, stream>>>(UV, 256, Mbuf, 128, stats + 0, stats + 512, Xcat);

  // stage 2: UV = Xcat[:, 128:256] @ W2cat^T (O=512)
  k_gemm<<<dim3(128, 8), 128, 0, stream>>>(Xcat, 512, 128, W2cat, 128, UV, 512, 128);
  k_gather<256><<<1024, 256, 0, stream>>>(UV, 512, 256, idxb, Mbuf, stats + 1024, stats + 2048);
  k_passB<256><<<16384, 256, 0, stream>>>(UV, 512, Mbuf, 256, stats + 1024, stats + 2048, Xcat);

  // fuse: Y3 = Xcat[:, 0:512] @ W3^T (O=128)
  k_gemm<<<dim3(128, 2), 128, 0, stream>>>(Xcat, 512, 0, W3, 512, Y3, 128, 512);
  k_stats3<<<1024, 128, 0, stream>>>(Y3, stats + 3072, stats + 3584);
  k_out<<<2048, 256, 0, stream>>>(Y3, stats + 3072, stats + 3584, out);
}

// Round 4
// 221.141 us; speedup vs baseline: 2.1450x; 1.6875x over previous
//
#include <hip/hip_runtime.h>
#include <math.h>
#include <stdint.h>

// Problem constants
#define NB 4
#define NC 128
#define NP 4096
#define KNN 10

// ---------------- ws layout (float-slot offsets) ----------------
// Xcat (bf16 u16) : [B][N][512]   @ 0         (4194304 float-slots = 16MB)
// UV   (f32)      : [B][N][512]   @ 4194304
// Mbuf (f32)      : [B][N][256]   @ 12582912  (Y3 aliases, [B][N][128])
// idx  (i32)      : [B][N][10]    @ 16777216
// W1cat (bf16)    : [256][128]    @ 16941056
// W2cat (bf16)    : [512][128]    @ 16957440
// W3b  (bf16)     : [128][512]    @ 16990208
// stats (f32)     : [8192]        @ 17022976
// KNN scratch aliases UV region (pre-GEMM only):
//   candd: [16384][160] @ UV+0 ; tq @ UV+2621440 ; cd @ UV+2637824
//   ci (int) @ UV+3031040 ; cnt (int) @ UV+3424256

__device__ __forceinline__ uint16_t f2bf(float f) {
  uint32_t u = __float_as_uint(f);
  u += 0x7fffu + ((u >> 16) & 1u);      // RNE
  return (uint16_t)(u >> 16);
}

__device__ __forceinline__ void async16(const void* g, void* l) {
  __builtin_amdgcn_global_load_lds(
      (const __attribute__((address_space(1))) unsigned int*)g,
      (__attribute__((address_space(3))) unsigned int*)l,
      16, 0, 0);
}

typedef __bf16 bf16x8 __attribute__((ext_vector_type(8)));
typedef float f32x4 __attribute__((ext_vector_type(4)));

__global__ void k_prep(const float* __restrict__ W1, const float* __restrict__ W2,
                       const float* __restrict__ W3,
                       uint16_t* __restrict__ W1cat, uint16_t* __restrict__ W2cat,
                       uint16_t* __restrict__ W3b,
                       float* __restrict__ stats, int* __restrict__ cnt) {
  int t = blockIdx.x * 256 + threadIdx.x;
  if (t < 32768) {
    int o = t >> 7, c = t & 127;
    float v;
    if (o < 128) v = W1[o * 256 + c] - W1[o * 256 + 128 + c];     // A1 = W1a - W1b
    else         v = W1[(o - 128) * 256 + 128 + c];               // B1 = W1b
    W1cat[t] = f2bf(v);
  } else if (t < 98304) {
    int t2 = t - 32768;
    int o = t2 >> 7, c = t2 & 127;
    float v;
    if (o < 256) v = W2[o * 256 + c] - W2[o * 256 + 128 + c];     // A2
    else         v = W2[(o - 256) * 256 + 128 + c];               // B2
    W2cat[t2] = f2bf(v);
  } else if (t < 163840) {
    int t2 = t - 98304;
    W3b[t2] = f2bf(W3[t2]);
  } else if (t < 163840 + 8192) {
    stats[t - 163840] = 0.f;
  } else if (t < 163840 + 8192 + 16384) {
    cnt[t - 163840 - 8192] = 0;
  }
}

// features [B][128][4096] (f32) -> Xcat[b][n][0:128] (bf16)
__global__ void k_trans_feat(const float* __restrict__ feat, uint16_t* __restrict__ Xcat) {
  __shared__ float tile[32][33];
  int bid = blockIdx.x;           // 2048
  int b = bid >> 9;
  int r = bid & 511;
  int n0 = (r >> 2) << 5;
  int c0 = (r & 3) << 5;
  int tx = threadIdx.x & 31, ty = threadIdx.x >> 5;   // 256 threads
#pragma unroll
  for (int i = 0; i < 4; i++) {
    int c = c0 + ty + i * 8;
    tile[ty + i * 8][tx] = feat[(b * 128 + c) * 4096 + n0 + tx];
  }
  __syncthreads();
#pragma unroll
  for (int i = 0; i < 4; i++) {
    int n = n0 + ty + i * 8;
    Xcat[((b * 4096 + n) * 512) + c0 + tx] = f2bf(tile[tx][ty + i * 8]);
  }
}

// ---------------- KNN: exact 2-phase threshold scheme (unchanged) ----------------
__global__ void k_knn_thr(const float* __restrict__ coords, float* __restrict__ candd) {
  __shared__ float4 sp[256];
  int L = blockIdx.x;             // 1024 = b(4) x qblk(16) x ch(16)
  int ch = L & 15;
  int qblk = (L >> 4) & 15;
  int b = L >> 8;
  int m0 = ch << 8;
  const float* cb = coords + b * 12288;
  int t = threadIdx.x;
  {
    int m = m0 + t;
    float x = cb[m], y = cb[4096 + m], z = cb[8192 + m];
    sp[t] = make_float4(x, y, z, x * x + y * y + z * z);
  }
  __syncthreads();
  int q = (qblk << 8) + t;
  float qx = cb[q], qy = cb[4096 + q], qz = cb[8192 + q];
  float qsq = fmaf(qx, qx, fmaf(qy, qy, qz * qz));
  float d10[10];
#pragma unroll
  for (int i = 0; i < 10; i++) d10[i] = 1e30f;
  if (ch == qblk) {
#pragma unroll 4
    for (int mm = 0; mm < 256; mm++) {
      float4 p = sp[mm];
      float dot = fmaf(qx, p.x, fmaf(qy, p.y, qz * p.z));
      float s = qsq + p.w;
      float d = fmaf(-2.f, dot, s);
      d = (m0 + mm == q) ? 1e30f : d;
      float carry = d;
#pragma unroll
      for (int i = 0; i < 10; i++) {
        float lo = fminf(d10[i], carry);
        carry = fmaxf(d10[i], carry);
        d10[i] = lo;
      }
    }
  } else {
#pragma unroll 4
    for (int mm = 0; mm < 256; mm++) {
      float4 p = sp[mm];
      float dot = fmaf(qx, p.x, fmaf(qy, p.y, qz * p.z));
      float s = qsq + p.w;
      float d = fmaf(-2.f, dot, s);
      float carry = d;
#pragma unroll
      for (int i = 0; i < 10; i++) {
        float lo = fminf(d10[i], carry);
        carry = fmaxf(d10[i], carry);
        d10[i] = lo;
      }
    }
  }
  int base = ((b * 4096 + q) * 16 + ch) * 10;
#pragma unroll
  for (int i = 0; i < 10; i++) candd[base + i] = d10[i];
}

__global__ void k_knn_merge(const float* __restrict__ candd, float* __restrict__ tq) {
  int q = blockIdx.x * 256 + threadIdx.x;  // 16384
  float d10[10];
#pragma unroll
  for (int i = 0; i < 10; i++) d10[i] = 1e30f;
  const float4* cp = (const float4*)(candd + q * 160);
  for (int j = 0; j < 40; j++) {
    float4 v4 = cp[j];
    float vs[4] = {v4.x, v4.y, v4.z, v4.w};
#pragma unroll
    for (int u = 0; u < 4; u++) {
      float carry = vs[u];
#pragma unroll
      for (int i = 0; i < 10; i++) {
        float lo = fminf(d10[i], carry);
        carry = fmaxf(d10[i], carry);
        d10[i] = lo;
      }
    }
  }
  tq[q] = d10[9];
}

__global__ void k_knn_collect(const float* __restrict__ coords, const float* __restrict__ tq,
                              int* __restrict__ cnt, float* __restrict__ cd, int* __restrict__ ci) {
  __shared__ float4 sp[256];
  int L = blockIdx.x;             // 1024
  int ch = L & 15;
  int qblk = (L >> 4) & 15;
  int b = L >> 8;
  int m0 = ch << 8;
  const float* cb = coords + b * 12288;
  int t = threadIdx.x;
  {
    int m = m0 + t;
    float x = cb[m], y = cb[4096 + m], z = cb[8192 + m];
    sp[t] = make_float4(x, y, z, x * x + y * y + z * z);
  }
  __syncthreads();
  int q = (qblk << 8) + t;
  int row = b * 4096 + q;
  float qx = cb[q], qy = cb[4096 + q], qz = cb[8192 + q];
  float qsq = fmaf(qx, qx, fmaf(qy, qy, qz * qz));
  float thr = tq[row];
  bool hs = (ch == qblk);
  for (int mm = 0; mm < 256; mm++) {
    float4 p = sp[mm];
    float dot = fmaf(qx, p.x, fmaf(qy, p.y, qz * p.z));
    float s = qsq + p.w;
    float d = fmaf(-2.f, dot, s);
    int m = m0 + mm;
    if (d <= thr && !(hs && m == q)) {
      int pos = atomicAdd(&cnt[row], 1);
      if (pos < 24) { cd[row * 24 + pos] = d; ci[row * 24 + pos] = m; }
    }
  }
}

__global__ void k_knn_final(const int* __restrict__ cnt, const float* __restrict__ cd,
                            const int* __restrict__ ci, int* __restrict__ idx) {
  int row = blockIdx.x * 256 + threadIdx.x;  // 16384
  int c = cnt[row]; c = c < 24 ? c : 24;
  float d10[10]; int i10[10];
#pragma unroll
  for (int i = 0; i < 10; i++) { d10[i] = 1e30f; i10[i] = 0x7fffffff; }
  for (int j = 0; j < c; j++) {
    float cdv = cd[row * 24 + j]; int civ = ci[row * 24 + j];
#pragma unroll
    for (int i = 0; i < 10; i++) {
      bool lt = (cdv < d10[i]) || (cdv == d10[i] && civ < i10[i]);
      float nd = lt ? cdv : d10[i]; int ni = lt ? civ : i10[i];
      float pd = lt ? d10[i] : cdv; int pi2 = lt ? i10[i] : civ;
      d10[i] = nd; i10[i] = ni; cdv = pd; civ = pi2;
    }
  }
#pragma unroll
  for (int i = 0; i < 10; i++) idx[row * 10 + i] = i10[i];
}

// ---------------- bf16 MFMA GEMM ----------------
// Y[p][o] = sum_k X[p][xoff+k] * W[o][k]   (X,W bf16; Y f32)
// BM=128, BN=64, BK=64. 256 threads = 4 waves (2x2). mfma 16x16x32.
// LDS: A[128][64] + B[64][64] bf16, double-buffered, XOR-swizzled:
//   element (r,k) at byte r*128 + ((k*2) ^ ((r&7)<<4)).
// Staged with global_load_lds(16B): linear LDS dest + inverse-swizzled
// global source (swizzle is an involution).
__global__ __launch_bounds__(256) void k_gemm_bf(
    const uint16_t* __restrict__ Xb, int ldx, int xoff,
    const uint16_t* __restrict__ Wb, int ldw,
    float* __restrict__ Y, int ldy, int K) {
  __shared__ __align__(16) uint8_t lds[49152];
  const int t = threadIdx.x;
  const int l = t & 63;
  const int wid = t >> 6;
  const int wr = wid & 1, wc = wid >> 1;
  const int p0 = blockIdx.x * 128;
  const int o0 = blockIdx.y * 64;

  const int rA = l >> 3;                         // row within 8-row chunk
  const int cbp = ((l & 7) ^ rA) << 4;           // pre-swizzled byte col (staging)
  const int swl = (l & 7) << 4;                  // read-side swizzle XOR

  f32x4 acc[4][2];
#pragma unroll
  for (int mi = 0; mi < 4; mi++)
#pragma unroll
    for (int ni = 0; ni < 2; ni++) acc[mi][ni] = (f32x4)0.f;

  auto stage = [&](int k0, int buf) {
    const uint16_t* Xs_ = Xb + (size_t)p0 * ldx + xoff + k0;
    const uint16_t* Ws_ = Wb + (size_t)o0 * ldw + k0;
#pragma unroll
    for (int cc = 0; cc < 4; cc++) {
      int c = wid * 4 + cc;                      // A chunk 0..15 -> rows c*8..c*8+8
      const uint8_t* g = (const uint8_t*)(Xs_ + (size_t)(c * 8 + rA) * ldx) + cbp;
      async16(g, &lds[buf * 16384 + c * 1024]);
    }
#pragma unroll
    for (int cc = 0; cc < 2; cc++) {
      int c = wid * 2 + cc;                      // B chunk 0..7
      const uint8_t* g = (const uint8_t*)(Ws_ + (size_t)(c * 8 + rA) * ldw) + cbp;
      async16(g, &lds[32768 + buf * 8192 + c * 1024]);
    }
  };

  auto compute = [&](int buf) {
    const uint8_t* Ab = &lds[buf * 16384];
    const uint8_t* Bb = &lds[32768 + buf * 8192];
#pragma unroll
    for (int ks = 0; ks < 2; ks++) {
      int cb = ks * 64 + ((l >> 4) << 4);
      bf16x8 bfr[2];
#pragma unroll
      for (int ni = 0; ni < 2; ni++) {
        int n = wc * 32 + ni * 16 + (l & 15);
        bfr[ni] = *(const bf16x8*)(Bb + n * 128 + (cb ^ swl));
      }
#pragma unroll
      for (int mi = 0; mi < 4; mi++) {
        int m = wr * 64 + mi * 16 + (l & 15);
        bf16x8 afr = *(const bf16x8*)(Ab + m * 128 + (cb ^ swl));
        acc[mi][0] = __builtin_amdgcn_mfma_f32_16x16x32_bf16(afr, bfr[0], acc[mi][0], 0, 0, 0);
        acc[mi][1] = __builtin_amdgcn_mfma_f32_16x16x32_bf16(afr, bfr[1], acc[mi][1], 0, 0, 0);
      }
    }
  };

  const int nsteps = K >> 6;
  stage(0, 0);
  for (int s = 0; s < nsteps; s++) {
    __syncthreads();                              // drains in-flight loads
    if (s + 1 < nsteps) stage((s + 1) << 6, (s + 1) & 1);
    compute(s & 1);
  }

#pragma unroll
  for (int mi = 0; mi < 4; mi++)
#pragma unroll
    for (int ni = 0; ni < 2; ni++) {
      int col = o0 + wc * 32 + ni * 16 + (l & 15);
      int row0 = p0 + wr * 64 + mi * 16 + (l >> 4) * 4;
#pragma unroll
      for (int j = 0; j < 4; j++)
        Y[(size_t)(row0 + j) * ldy + col] = acc[mi][ni][j];
    }
}

// Gather pass (unchanged, fp32 UV)
template <int O>
__global__ void k_gather(const float* __restrict__ UV, int ld, int voff,
                         const int* __restrict__ idx,
                         float* __restrict__ M,
                         float* __restrict__ T1, float* __restrict__ T2) {
  int L = blockIdx.x;             // 1024 blocks
  int rx = L & 7;
  int b = rx >> 1;
  int j = ((L >> 3) << 1) + (rx & 1);
  int n0 = j << 4;
  int o = threadIdx.x;
  float a1 = 0.f, a2 = 0.f;
  for (int pi = 0; pi < 16; pi++) {
    int row = b * 4096 + n0 + pi;
    float u = UV[row * ld + o];
    float s1 = 0.f, s2 = 0.f, vmax = -1e30f;
#pragma unroll
    for (int jj = 0; jj < KNN; jj++) {
      int m = idx[row * 10 + jj];
      float v = UV[(b * 4096 + m) * ld + voff + o];
      s1 += v;
      float x = u + v;
      s2 = fmaf(x, x, s2);
      vmax = fmaxf(vmax, v);
    }
    M[row * O + o] = vmax;
    a1 += 10.f * u + s1;
    a2 += s2;
  }
  atomicAdd(&T1[b * O + o], a1);
  atomicAdd(&T2[b * O + o], a2);
}

// x = lrelu((U + maxV - mu) * rsqrt(var+eps)) -> Xcat[:, coff:coff+O] (bf16)
template <int O>
__global__ void k_passB(const float* __restrict__ UV, int ld,
                        const float* __restrict__ M, int coff,
                        const float* __restrict__ T1, const float* __restrict__ T2,
                        uint16_t* __restrict__ Xcat) {
  int t = blockIdx.x * 256 + threadIdx.x;
  int o = t & (O - 1);
  int pn = t / O;
  int b = pn >> 12;
  float mu = T1[b * O + o] * (1.f / 40960.f);
  float e2 = T2[b * O + o] * (1.f / 40960.f);
  float inv = rsqrtf(e2 - mu * mu + 1e-5f);
  float x = (UV[pn * ld + o] + M[pn * O + o] - mu) * inv;
  Xcat[pn * 512 + coff + o] = f2bf(x >= 0.f ? x : 0.2f * x);
}

__global__ void k_stats3(const float* __restrict__ Y3, float* __restrict__ T1, float* __restrict__ T2) {
  int L = blockIdx.x;             // 1024
  int rx = L & 7;
  int b = rx >> 1;
  int j = ((L >> 3) << 1) + (rx & 1);
  int n0 = j << 4;
  int o = threadIdx.x;            // 128
  float a1 = 0.f, a2 = 0.f;
  for (int pi = 0; pi < 16; pi++) {
    float y = Y3[(b * 4096 + n0 + pi) * 128 + o];
    a1 += y;
    a2 = fmaf(y, y, a2);
  }
  atomicAdd(&T1[b * 128 + o], a1);
  atomicAdd(&T2[b * 128 + o], a2);
}

// out[b][o][n] = lrelu((Y3[b][n][o]-mu)*inv)  (transposing write)
__global__ void k_out(const float* __restrict__ Y3, const float* __restrict__ T1,
                      const float* __restrict__ T2, float* __restrict__ out) {
  __shared__ float tile[32][33];
  int bid = blockIdx.x;           // 2048
  int b = bid >> 9;
  int r = bid & 511;
  int n0 = (r >> 2) << 5;
  int o0 = (r & 3) << 5;
  int tx = threadIdx.x & 31, ty = threadIdx.x >> 5;
  int o = o0 + tx;
  float mu = T1[b * 128 + o] * (1.f / 4096.f);
  float e2 = T2[b * 128 + o] * (1.f / 4096.f);
  float inv = rsqrtf(e2 - mu * mu + 1e-5f);
#pragma unroll
  for (int i = 0; i < 4; i++) {
    int n = n0 + ty + i * 8;
    float v = (Y3[(b * 4096 + n) * 128 + o] - mu) * inv;
    tile[ty + i * 8][tx] = v >= 0.f ? v : 0.2f * v;
  }
  __syncthreads();
#pragma unroll
  for (int i = 0; i < 4; i++) {
    int oo = o0 + ty + i * 8;
    out[(b * 128 + oo) * 4096 + n0 + tx] = tile[tx][ty + i * 8];
  }
}

extern "C" void kernel_launch(void* const* d_in, const int* in_sizes, int n_in,
                              void* d_out, int out_size, void* d_ws, size_t ws_size,
                              hipStream_t stream) {
  const float* coords   = (const float*)d_in[0];
  const float* features = (const float*)d_in[1];
  const float* W1       = (const float*)d_in[2];
  const float* W2       = (const float*)d_in[3];
  const float* W3       = (const float*)d_in[4];
  float* out = (float*)d_out;

  float*    ws    = (float*)d_ws;
  uint16_t* Xcat  = (uint16_t*)ws;                 // bf16 [4][4096][512]
  float*    UV    = ws + 4194304;
  float*    Mbuf  = ws + 12582912;
  float*    Y3    = Mbuf;                          // alias (M dead by fuse GEMM)
  int*      idxb  = (int*)(ws + 16777216);
  uint16_t* W1cat = (uint16_t*)(ws + 16941056);
  uint16_t* W2cat = (uint16_t*)(ws + 16957440);
  uint16_t* W3b   = (uint16_t*)(ws + 16990208);
  float*    stats = ws + 17022976;
  // KNN scratch aliases UV region (used only before stage-1 GEMM)
  float* candd = UV;
  float* tq    = UV + 2621440;
  float* cd    = UV + 2637824;
  int*   ci    = (int*)(UV + 3031040);
  int*   cnt   = (int*)(UV + 3424256);

  k_prep<<<736, 256, 0, stream>>>(W1, W2, W3, W1cat, W2cat, W3b, stats, cnt);
  k_trans_feat<<<2048, 256, 0, stream>>>(features, Xcat);
  k_knn_thr<<<1024, 256, 0, stream>>>(coords, candd);
  k_knn_merge<<<64, 256, 0, stream>>>(candd, tq);
  k_knn_collect<<<1024, 256, 0, stream>>>(coords, tq, cnt, cd, ci);
  k_knn_final<<<64, 256, 0, stream>>>(cnt, cd, ci, idxb);

  // stage 1: UV = Xcat[:, 0:128] @ W1cat^T  (O=256)
  k_gemm_bf<<<dim3(128, 4), 256, 0, stream>>>(Xcat, 512, 0, W1cat, 128, UV, 256, 128);
  k_gather<128><<<1024, 128, 0, stream>>>(UV, 256, 128, idxb, Mbuf, stats + 0, stats + 512);
  k_passB<128><<<8192, 256, 0, stream>>>(UV, 256, Mbuf, 128, stats + 0, stats + 512, Xcat);

  // stage 2: UV = Xcat[:, 128:256] @ W2cat^T (O=512)
  k_gemm_bf<<<dim3(128, 8), 256, 0, stream>>>(Xcat, 512, 128, W2cat, 128, UV, 512, 128);
  k_gather<256><<<1024, 256, 0, stream>>>(UV, 512, 256, idxb, Mbuf, stats + 1024, stats + 2048);
  k_passB<256><<<16384, 256, 0, stream>>>(UV, 512, Mbuf, 256, stats + 1024, stats + 2048, Xcat);

  // fuse: Y3 = Xcat[:, 0:512] @ W3b^T (O=128)
  k_gemm_bf<<<dim3(128, 2), 256, 0, stream>>>(Xcat, 512, 0, W3b, 512, Y3, 128, 512);
  k_stats3<<<1024, 128, 0, stream>>>(Y3, stats + 3072, stats + 3584);
  k_out<<<2048, 256, 0, stream>>>(Y3, stats + 3072, stats + 3584, out);
}